// Round 5
// baseline (384.543 us; speedup 1.0000x reference)
//
#include <hip/hip_runtime.h>

// BahdanauAttnDecoderRNN single-step decode, MI355X — single kernel, DAG sync.
// Reference dead code: softmax over size-1 axis => attn_weights == 1.0;
// attn_W/attn_b/scores dead; attn_applied = colsum(encoder_outputs).
// Live work ~178 MB f32 reads (Wout 131 MB dominant) => ~28 us HBM roofline.
// R2 (5 dispatches): 62.5 us — ~6 us/dispatch boundary tax.
// R4 (coop + 3x grid.sync): 224 us — cg grid barrier ~60 us each (1024 blocks
// spinning one cacheline across 8 non-coherent XCD L2s; VALUBusy 2.9%).
// R5: one kernel, scoped low-contention signals instead of full barriers:
//   ctrA(64 arrivals/8 pollers) -> ctrA2(8/192) -> ctrB striped x16 (1024/1)
//   -> block 0 computes gates, sets 16 mirrored flags -> all blocks do logits
//   (each prefetched its own Wout task into L2 while waiting) -> ctrC striped
//   x8 -> 125 finalize blocks. Producers: threadfence+atomicAdd (release);
//   consumers: relaxed atomic poll + threadfence (acquire). Spin bailouts.

namespace {
constexpr int H = 1024;
constexpr int V = 32000;
constexpr int S = 2048;
constexpr int NB = 1024;          // 4 blocks/CU x 256 CU, co-resident
constexpr int NTHR = 256;
constexpr int CS_CHUNKS = 64;     // colsum chunks
constexpr int CS_ROWS = S / CS_CHUNKS;   // 32
constexpr int ST2_BLKS = 8;       // colsum finisher blocks
constexpr int ST2_COLS = H / ST2_BLKS;   // 128
constexpr int GI2_BLKS = 192;     // gi2 matvec blocks
constexpr int GI2_ROWS = 16;      // 192*16 = 3072
constexpr int GH_BASE = 192;
constexpr int GH_BLKS = 768;      // 4 rows each -> 3072
constexpr int ONES_BID = 960;
constexpr int LT_TASKS = 2000;    // logits tasks, 16 rows each -> 32000
constexpr int FIN_BLKS = 125;     // 125*256 = 32000
constexpr int NWAVE = NB * 4;
// sync region (ints, 128B-strided slots), zeroed by memset each call
constexpr int CTRA = 0;           // 1 counter
constexpr int CTRA2 = 32;         // 1 counter
constexpr int CTRB = 64;          // 16 stripes: +32*s
constexpr int FLAG2 = 576;        // 16 mirrors: +32*m
constexpr int CTRC = 1088;        // 8 stripes: +32*s
constexpr int SYNC_INTS = 2048;   // 8 KB
constexpr int SPIN_LIMIT = 3000000;
}

struct Ptrs {
    const int* word; const float* hin; const float* enc; const float* emb;
    const float* Wih; const float* Whh; const float* bih; const float* bhh;
    const float* Wout; const float* bout;
    float* out; int* sync;
    float* part; float* rnG; float* gi; float* gi2; float* gh;
    float* hnewG; float* logits; float* partm; float* parts; float* dummy;
};

__device__ __forceinline__ float wave_sum(float v) {
#pragma unroll
    for (int off = 32; off > 0; off >>= 1) v += __shfl_xor(v, off, 64);
    return v;
}
__device__ __forceinline__ float wave_max(float v) {
#pragma unroll
    for (int off = 32; off > 0; off >>= 1) v = fmaxf(v, __shfl_xor(v, off, 64));
    return v;
}
__device__ __forceinline__ int aload(const int* p) {
    return __hip_atomic_load(p, __ATOMIC_RELAXED, __HIP_MEMORY_SCOPE_AGENT);
}
__device__ __forceinline__ void spin_until(const int* p, int target) {
    int it = 0;
    while (aload(p) < target && it < SPIN_LIMIT) { __builtin_amdgcn_s_sleep(4); ++it; }
}
__device__ __forceinline__ void spin_sum(const int* base, int n, int target) {
    int it = 0;
    for (;;) {
        int s = 0;
        for (int k = 0; k < n; ++k) s += aload(base + 32 * k);
        if (s >= target || it >= SPIN_LIMIT) break;
        __builtin_amdgcn_s_sleep(4); ++it;
    }
}

// Prefetch this block's first logits task (16 Wout rows, 64 KB) into local L2.
__device__ __forceinline__ void prefetch_task(const Ptrs& P, int bid) {
    const int t = threadIdx.x;
    const float4* base = (const float4*)P.Wout + (size_t)bid * 16 * (H / 4);
    float acc = 0.f;
#pragma unroll
    for (int k = 0; k < 16; ++k) {
        float4 v = base[k * 256 + t];
        acc += v.x + v.y + v.z + v.w;
    }
    if (acc == 1.234567e38f) P.dummy[bid] = acc;  // keep-alive, never true
}

__global__ __launch_bounds__(NTHR, 4) void dag(Ptrs P) {
    const int bid = blockIdx.x, t = threadIdx.x, lane = t & 63, w = t >> 6;
    int* sync = P.sync;
    __shared__ float4 sh4[H / 4];
    __shared__ float red[8];

    // ---- A: colsum chunks (blocks 0..63)
    if (bid < CS_CHUNKS) {
        const float4* e = (const float4*)P.enc + (size_t)bid * CS_ROWS * (H / 4) + t;
        float4 acc = make_float4(0.f, 0.f, 0.f, 0.f);
#pragma unroll
        for (int r = 0; r < CS_ROWS; ++r) {
            float4 v = e[(size_t)r * (H / 4)];
            acc.x += v.x; acc.y += v.y; acc.z += v.z; acc.w += v.w;
        }
        ((float4*)P.part)[bid * (H / 4) + t] = acc;
        __threadfence(); __syncthreads();
        if (t == 0) atomicAdd(sync + CTRA, 1);
    }

    // ---- B: colsum finish -> relu'd colsum (blocks 0..7)
    if (bid < ST2_BLKS) {
        if (t == 0) spin_until(sync + CTRA, CS_CHUNKS);
        __syncthreads(); __threadfence();
        if (t < ST2_COLS) {
            const int col = bid * ST2_COLS + t;
            float s = 0.f;
            for (int p = 0; p < CS_CHUNKS; ++p) s += P.part[p * H + col];
            P.rnG[col] = fmaxf(s, 0.f);
        }
        __threadfence(); __syncthreads();
        if (t == 0) atomicAdd(sync + CTRA2, 1);
    }

    // ---- C: pre-gates work per role, then arrive ctrB (all 1024 blocks)
    bool prefetched = false;
    if (bid < GI2_BLKS) {
        if (bid >= CS_CHUNKS) {  // 64..191 idle until ctrA2: prefetch first
            prefetch_task(P, bid);
            prefetched = true;
        }
        if (t == 0) spin_until(sync + CTRA2, ST2_BLKS);
        __syncthreads(); __threadfence();
        sh4[t] = ((const float4*)P.rnG)[t];
        __syncthreads();
#pragma unroll
        for (int i = 0; i < 4; ++i) {
            const int row = bid * GI2_ROWS + w * 4 + i;  // < 3072
            const float4* wr = (const float4*)P.Wih + (size_t)row * (2 * H / 4) + (H / 4);
            float a = 0.f;
#pragma unroll
            for (int it = 0; it < 4; ++it) {
                const int idx = it * 64 + lane;
                float4 wv = wr[idx], x = sh4[idx];
                a += wv.x * x.x + wv.y * x.y + wv.z * x.z + wv.w * x.w;
            }
            a = wave_sum(a);
            if (lane == 0) P.gi2[row] = a;
        }
        __threadfence(); __syncthreads();
        if (t == 0) atomicAdd(sync + CTRB + 32 * (bid & 15), 1);
    } else {
        if (bid >= GH_BASE && bid < GH_BASE + GH_BLKS) {
            const int row = (bid - GH_BASE) * 4 + w;  // < 3072
            const float4* wh = (const float4*)P.Whh + (size_t)row * (H / 4);
            const float4* xh = (const float4*)P.hin;
            const float4* wi = (const float4*)P.Wih + (size_t)row * (2 * H / 4);
            const float4* er = (const float4*)P.emb + (size_t)P.word[0] * (H / 4);
            float ah = 0.f, ai = 0.f;
#pragma unroll
            for (int it = 0; it < 4; ++it) {
                const int idx = it * 64 + lane;
                float4 a4 = wh[idx], x4 = xh[idx];
                ah += a4.x * x4.x + a4.y * x4.y + a4.z * x4.z + a4.w * x4.w;
                float4 b4 = wi[idx], e4 = er[idx];
                e4.x = fmaxf(e4.x, 0.f); e4.y = fmaxf(e4.y, 0.f);
                e4.z = fmaxf(e4.z, 0.f); e4.w = fmaxf(e4.w, 0.f);
                ai += b4.x * e4.x + b4.y * e4.y + b4.z * e4.z + b4.w * e4.w;
            }
            ah = wave_sum(ah);
            ai = wave_sum(ai);
            if (lane == 0) {
                P.gh[row] = ah + P.bhh[row];
                P.gi[row] = ai + P.bih[row];  // emb half (+bias); gi2 added at gates
            }
        }
        if (bid == ONES_BID) {
#pragma unroll
            for (int k = 0; k < S / NTHR; ++k) P.out[V + H + k * NTHR + t] = 1.0f;
        }
        __threadfence(); __syncthreads();
        if (t == 0) atomicAdd(sync + CTRB + 32 * (bid & 15), 1);
        prefetch_task(P, bid);  // after arrival: never delays the gates
        prefetched = true;
    }

    // ---- D: gates + h_new by block 0; others wait on mirrored flags
    if (bid == 0) {
        if (t == 0) spin_sum(sync + CTRB, 16, NB);
        __syncthreads(); __threadfence();
#pragma unroll
        for (int q = 0; q < 4; ++q) {
            const int j = q * NTHR + t;
            const float gr = P.gi[j] + P.gi2[j] + P.gh[j];
            const float gz = P.gi[H + j] + P.gi2[H + j] + P.gh[H + j];
            const float r = 1.f / (1.f + expf(-gr));
            const float z = 1.f / (1.f + expf(-gz));
            const float n = tanhf(P.gi[2 * H + j] + P.gi2[2 * H + j] + r * P.gh[2 * H + j]);
            const float hv = (1.f - z) * n + z * P.hin[j];
            P.hnewG[j] = hv;
            P.out[V + j] = hv;  // hidden-state output
        }
        __threadfence(); __syncthreads();
        if (t == 0) {
#pragma unroll
            for (int m = 0; m < 16; ++m)
                __hip_atomic_store(sync + FLAG2 + 32 * m, 1, __ATOMIC_RELAXED,
                                   __HIP_MEMORY_SCOPE_AGENT);
        }
    } else {
        if (!prefetched) prefetch_task(P, bid);  // blocks 1..63
        if (t == 0) {
            int it = 0;
            while (aload(sync + FLAG2 + 32 * (bid & 15)) == 0 && it < SPIN_LIMIT) {
                __builtin_amdgcn_s_sleep(4); ++it;
            }
        }
        __syncthreads(); __threadfence();
    }

    // ---- E: logits matvec + per-wave softmax partials (all blocks)
    __syncthreads();
    sh4[t] = ((const float4*)P.hnewG)[t];
    __syncthreads();
    float m = -3.4e38f, ssum = 0.f;
    for (int task = bid; task < LT_TASKS; task += NB) {
#pragma unroll
        for (int i = 0; i < 4; ++i) {
            const int row = task * 16 + w * 4 + i;  // < 32000
            const float4* wr = (const float4*)P.Wout + (size_t)row * (H / 4);
            float a = 0.f;
#pragma unroll
            for (int it = 0; it < 4; ++it) {
                const int idx = it * 64 + lane;
                float4 wv = wr[idx], x = sh4[idx];
                a += wv.x * x.x + wv.y * x.y + wv.z * x.z + wv.w * x.w;
            }
            a = wave_sum(a) + P.bout[row];  // identical on all lanes
            if (lane == 0) P.logits[row] = a;
            const float mn = fmaxf(m, a);
            ssum = ssum * expf(m - mn) + expf(a - mn);
            m = mn;
        }
    }
    if (lane == 0) { P.partm[bid * 4 + w] = m; P.parts[bid * 4 + w] = ssum; }
    __threadfence(); __syncthreads();
    if (t == 0) atomicAdd(sync + CTRC + 32 * (bid & 7), 1);

    // ---- F: finalize (blocks 0..124): redundant fixed-order reduce + apply
    if (bid < FIN_BLKS) {
        if (t == 0) spin_sum(sync + CTRC, 8, NB);
        __syncthreads(); __threadfence();
        float mm = -3.4e38f;
        for (int k = t; k < NWAVE; k += NTHR) mm = fmaxf(mm, P.partm[k]);
        mm = wave_max(mm);
        if (lane == 0) red[w] = mm;
        __syncthreads();
        const float M = fmaxf(fmaxf(red[0], red[1]), fmaxf(red[2], red[3]));
        float s = 0.f;
        for (int k = t; k < NWAVE; k += NTHR) s += P.parts[k] * expf(P.partm[k] - M);
        s = wave_sum(s);
        __syncthreads();
        if (lane == 0) red[w] = s;
        __syncthreads();
        const float L = logf(red[0] + red[1] + red[2] + red[3]);
        const int g = bid * NTHR + t;
        P.out[g] = P.logits[g] - M - L;
    }
}

extern "C" void kernel_launch(void* const* d_in, const int* in_sizes, int n_in,
                              void* d_out, int out_size, void* d_ws, size_t ws_size,
                              hipStream_t stream) {
    Ptrs P;
    P.word = (const int*)d_in[0];
    P.hin  = (const float*)d_in[1];
    P.enc  = (const float*)d_in[2];
    P.emb  = (const float*)d_in[3];
    // d_in[4] attn_W, d_in[5] attn_b: dead (softmax over size-1 axis)
    P.Wih  = (const float*)d_in[6];
    P.Whh  = (const float*)d_in[7];
    P.bih  = (const float*)d_in[8];
    P.bhh  = (const float*)d_in[9];
    P.Wout = (const float*)d_in[10];
    P.bout = (const float*)d_in[11];
    P.out  = (float*)d_out;
    P.sync = (int*)d_ws;
    float* data = (float*)d_ws + 4096;  // skip 16 KB sync region
    P.part   = data;                    // [64*1024]
    P.rnG    = P.part + CS_CHUNKS * H;  // [1024]
    P.gi     = P.rnG + H;               // [3072]
    P.gi2    = P.gi + 3 * H;            // [3072]
    P.gh     = P.gi2 + 3 * H;           // [3072]
    P.hnewG  = P.gh + 3 * H;            // [1024]
    P.logits = P.hnewG + H;             // [32000]
    P.partm  = P.logits + V;            // [4096]
    P.parts  = P.partm + NWAVE;         // [4096]
    P.dummy  = P.parts + NWAVE;         // [1024]

    // reset sync counters/flags (poisoned or stale from previous replay)
    hipMemsetAsync(d_ws, 0, SYNC_INTS * sizeof(int), stream);

    int dev = 0;
    (void)hipGetDevice(&dev);
    int coop = 0;
    (void)hipDeviceGetAttribute(&coop, hipDeviceAttributeCooperativeLaunch, dev);
    bool done = false;
    if (coop) {
        void* args[] = {(void*)&P};
        done = hipLaunchCooperativeKernel((void*)dag, dim3(NB), dim3(NTHR),
                                          args, 0, stream) == hipSuccess;
    }
    if (!done) dag<<<NB, NTHR, 0, stream>>>(P);
}

// Round 6
// 60.738 us; speedup vs baseline: 6.3312x; 6.3312x over previous
//
#include <hip/hip_runtime.h>

// BahdanauAttnDecoderRNN single-step decode, MI355X — 4 stream-ordered kernels.
// Reference dead code: softmax over size-1 axis => attn_weights == 1.0;
// attn_W/attn_b/scores dead; attn_applied = colsum(encoder_outputs).
// Live work ~178 MB f32 reads (Wout 131 MB dominant) => ~28 us HBM roofline.
// Sync lesson (R4: coop grid.sync 441 us; R5: custom DAG flags 486 us, HBM
// collapsed to 250 GB/s): intra-kernel cross-XCD sync destroys streaming BW
// on this chip. Use plain dispatch boundaries (~5 us each), minimize count:
//   D1: colsum partials (32 chunks) + gh + emb-half gi + attn ones   (~6 us)
//   D2: redundant partial-reduce + colsum-half gi2                   (~3 us)
//   D3: gates REDUNDANT per block (kills a dispatch) + logits matvec
//       + raw logits to d_out + per-wave online softmax partials     (~20 us)
//   D4: fixed-order partial reduce + in-place log-softmax            (~2 us)

namespace {
constexpr int H = 1024;
constexpr int V = 32000;
constexpr int S = 2048;
constexpr int NTHR = 256;
constexpr int CS_BLKS = 32;             // colsum chunks
constexpr int CS_ROWS = S / CS_BLKS;    // 64 rows per chunk
constexpr int GRU_BLKS = 768;           // 3072 rows / 4 per block
constexpr int D1_BLKS = CS_BLKS + GRU_BLKS + 1;  // 801
constexpr int D2_BLKS = 192;            // 16 gi2 rows each
constexpr int D3_BLKS = 2000;           // 16 logits rows each
constexpr int NPART = D3_BLKS * 4;      // 8000 per-wave partials
constexpr int D4_BLKS = V / NTHR;       // 125
}

__device__ __forceinline__ float wave_sum(float v) {
#pragma unroll
    for (int off = 32; off > 0; off >>= 1) v += __shfl_xor(v, off, 64);
    return v;
}
__device__ __forceinline__ float wave_max(float v) {
#pragma unroll
    for (int off = 32; off > 0; off >>= 1) v = fmaxf(v, __shfl_xor(v, off, 64));
    return v;
}

// D1: colsum partials + gh & emb-half of gi + attn ones.
__global__ __launch_bounds__(NTHR) void k_front(
    const float* __restrict__ enc, const float* __restrict__ Whh,
    const float* __restrict__ Wih, const float* __restrict__ bih,
    const float* __restrict__ bhh, const float* __restrict__ hin,
    const float* __restrict__ emb, const int* __restrict__ word,
    float* __restrict__ part, float* __restrict__ gi, float* __restrict__ gh,
    float* __restrict__ out) {
    const int b = blockIdx.x, t = threadIdx.x;
    if (b < CS_BLKS) {
        // rows [b*64, b*64+64); thread t owns float4-column t
        const float4* e = (const float4*)enc + (size_t)b * CS_ROWS * (H / 4) + t;
        float4 acc = make_float4(0.f, 0.f, 0.f, 0.f);
#pragma unroll
        for (int r = 0; r < CS_ROWS; ++r) {
            float4 v = e[(size_t)r * (H / 4)];
            acc.x += v.x; acc.y += v.y; acc.z += v.z; acc.w += v.w;
        }
        ((float4*)part)[b * (H / 4) + t] = acc;
    } else if (b < CS_BLKS + GRU_BLKS) {
        const int lane = t & 63, w = t >> 6;
        const int row = (b - CS_BLKS) * 4 + w;  // < 3072
        const float4* wh = (const float4*)Whh + (size_t)row * (H / 4);
        const float4* xh = (const float4*)hin;
        const float4* wi = (const float4*)Wih + (size_t)row * (2 * H / 4);
        const float4* er = (const float4*)emb + (size_t)word[0] * (H / 4);
        float ah = 0.f, ai = 0.f;
#pragma unroll
        for (int it = 0; it < 4; ++it) {
            const int idx = it * 64 + lane;
            float4 a4 = wh[idx], x4 = xh[idx];
            ah += a4.x * x4.x + a4.y * x4.y + a4.z * x4.z + a4.w * x4.w;
            float4 b4 = wi[idx], e4 = er[idx];
            e4.x = fmaxf(e4.x, 0.f); e4.y = fmaxf(e4.y, 0.f);
            e4.z = fmaxf(e4.z, 0.f); e4.w = fmaxf(e4.w, 0.f);
            ai += b4.x * e4.x + b4.y * e4.y + b4.z * e4.z + b4.w * e4.w;
        }
        ah = wave_sum(ah);
        ai = wave_sum(ai);
        if (lane == 0) {
            gh[row] = ah + bhh[row];
            gi[row] = ai + bih[row];  // colsum half lives in gi2
        }
    } else {
        // attn_weights are exactly 1.0 (softmax over size-1 axis)
#pragma unroll
        for (int k = 0; k < S / NTHR; ++k) out[V + H + k * NTHR + t] = 1.0f;
    }
}

// D2: per-block redundant reduce of 32 colsum partials -> relu -> LDS;
// then 16 rows of gi2 = Wih[:, H:2H] . rn.
__global__ __launch_bounds__(NTHR) void k_gi2(
    const float* __restrict__ Wih, const float* __restrict__ part,
    float* __restrict__ gi2) {
    __shared__ float4 rn[H / 4];
    const int t = threadIdx.x, lane = t & 63, w = t >> 6;
    float4 acc = make_float4(0.f, 0.f, 0.f, 0.f);
#pragma unroll
    for (int c = 0; c < CS_BLKS; ++c) {
        float4 v = ((const float4*)part)[c * (H / 4) + t];
        acc.x += v.x; acc.y += v.y; acc.z += v.z; acc.w += v.w;
    }
    acc.x = fmaxf(acc.x, 0.f); acc.y = fmaxf(acc.y, 0.f);
    acc.z = fmaxf(acc.z, 0.f); acc.w = fmaxf(acc.w, 0.f);
    rn[t] = acc;
    __syncthreads();
#pragma unroll
    for (int i = 0; i < 4; ++i) {
        const int row = blockIdx.x * 16 + w * 4 + i;  // < 3072
        const float4* wr = (const float4*)Wih + (size_t)row * (2 * H / 4) + (H / 4);
        float a = 0.f;
#pragma unroll
        for (int it = 0; it < 4; ++it) {
            const int idx = it * 64 + lane;
            float4 wv = wr[idx], x = rn[idx];
            a += wv.x * x.x + wv.y * x.y + wv.z * x.z + wv.w * x.w;
        }
        a = wave_sum(a);
        if (lane == 0) gi2[row] = a;
    }
}

// D3: gates redundant per block -> h_new in LDS -> 16-row Wout matvec ->
// raw logits into d_out + per-wave online softmax partials.
__global__ __launch_bounds__(NTHR) void k_logits(
    const float* __restrict__ gi, const float* __restrict__ gi2,
    const float* __restrict__ gh, const float* __restrict__ hin,
    const float* __restrict__ Wout, const float* __restrict__ bout,
    float* __restrict__ out, float* __restrict__ partm, float* __restrict__ parts) {
    __shared__ float hnew[H];
    const int t = threadIdx.x, lane = t & 63, w = t >> 6;
#pragma unroll
    for (int q = 0; q < 4; ++q) {
        const int j = q * NTHR + t;
        const float gr = gi[j] + gi2[j] + gh[j];
        const float gz = gi[H + j] + gi2[H + j] + gh[H + j];
        const float r = 1.f / (1.f + expf(-gr));
        const float z = 1.f / (1.f + expf(-gz));
        const float n = tanhf(gi[2 * H + j] + gi2[2 * H + j] + r * gh[2 * H + j]);
        const float hv = (1.f - z) * n + z * hin[j];
        hnew[j] = hv;
        if (blockIdx.x == 0) out[V + j] = hv;  // hidden-state output
    }
    __syncthreads();
    const float4* hn4 = (const float4*)hnew;
    float m = -3.4e38f, ssum = 0.f;
#pragma unroll
    for (int i = 0; i < 4; ++i) {
        const int row = blockIdx.x * 16 + w * 4 + i;  // < 32000
        const float4* wr = (const float4*)Wout + (size_t)row * (H / 4);
        float a = 0.f;
#pragma unroll
        for (int it = 0; it < 4; ++it) {
            const int idx = it * 64 + lane;
            float4 wv = wr[idx], x = hn4[idx];
            a += wv.x * x.x + wv.y * x.y + wv.z * x.z + wv.w * x.w;
        }
        a = wave_sum(a) + bout[row];  // identical on all lanes
        if (lane == 0) out[row] = a;  // raw logit
        const float mn = fmaxf(m, a);
        ssum = ssum * expf(m - mn) + expf(a - mn);
        m = mn;
    }
    if (lane == 0) { partm[blockIdx.x * 4 + w] = m; parts[blockIdx.x * 4 + w] = ssum; }
}

// D4: redundant fixed-order reduce of 8000 partials + in-place log-softmax.
__global__ __launch_bounds__(NTHR) void k_final(
    const float* __restrict__ partm, const float* __restrict__ parts,
    float* __restrict__ out) {
    __shared__ float ms[4], ss[4];
    const int t = threadIdx.x, lane = t & 63, w = t >> 6;
    float m = -3.4e38f;
    for (int k = t; k < NPART; k += NTHR) m = fmaxf(m, partm[k]);
    m = wave_max(m);
    if (lane == 0) ms[w] = m;
    __syncthreads();
    const float M = fmaxf(fmaxf(ms[0], ms[1]), fmaxf(ms[2], ms[3]));
    float s = 0.f;
    for (int k = t; k < NPART; k += NTHR) s += parts[k] * expf(partm[k] - M);
    s = wave_sum(s);
    if (lane == 0) ss[w] = s;
    __syncthreads();
    const float L = logf(ss[0] + ss[1] + ss[2] + ss[3]);
    const int g = blockIdx.x * NTHR + t;  // 125*256 = 32000
    out[g] = out[g] - M - L;
}

extern "C" void kernel_launch(void* const* d_in, const int* in_sizes, int n_in,
                              void* d_out, int out_size, void* d_ws, size_t ws_size,
                              hipStream_t stream) {
    const int*   word = (const int*)d_in[0];
    const float* hin  = (const float*)d_in[1];
    const float* enc  = (const float*)d_in[2];
    const float* emb  = (const float*)d_in[3];
    // d_in[4] attn_W, d_in[5] attn_b: dead (softmax over size-1 axis)
    const float* Wih  = (const float*)d_in[6];
    const float* Whh  = (const float*)d_in[7];
    const float* bih  = (const float*)d_in[8];
    const float* bhh  = (const float*)d_in[9];
    const float* Wout = (const float*)d_in[10];
    const float* bout = (const float*)d_in[11];
    float* out = (float*)d_out;
    float* ws  = (float*)d_ws;

    float* part  = ws;                  // [32*1024]
    float* gi    = part + CS_BLKS * H;  // [3072]
    float* gi2   = gi + 3 * H;          // [3072]
    float* gh    = gi2 + 3 * H;         // [3072]
    float* partm = gh + 3 * H;          // [8000]
    float* parts = partm + NPART;       // [8000]

    k_front<<<D1_BLKS, NTHR, 0, stream>>>(enc, Whh, Wih, bih, bhh, hin, emb, word,
                                          part, gi, gh, out);
    k_gi2<<<D2_BLKS, NTHR, 0, stream>>>(Wih, part, gi2);
    k_logits<<<D3_BLKS, NTHR, 0, stream>>>(gi, gi2, gh, hin, Wout, bout, out,
                                           partm, parts);
    k_final<<<D4_BLKS, NTHR, 0, stream>>>(partm, parts, out);
}